// Round 5
// baseline (337.966 us; speedup 1.0000x reference)
//
#include <hip/hip_runtime.h>

#define N_NODES 50000
#define N_EDGES 800000
#define DIM 128
#define WT_BLOCKS 192              // 3 * 128*128 / 256
#define GEMM_BLOCKS ((N_NODES + 127) / 128)
#define FUSE_BLOCKS ((N_NODES + 63) / 64)     // fused agg+gemm: 64 rows/block
#define NBUCKET ((N_NODES + 255) / 256)   // 196 buckets of 256 nodes (bucket = dst>>8)
#define P1_BLOCKS 200
#define P1_CHUNK 4000              // P1_BLOCKS * P1_CHUNK == N_EDGES
#define P2_BLOCKS 200
#define P2_CHUNK 4000

typedef unsigned int u32;
typedef short bf16x8 __attribute__((ext_vector_type(8)));
typedef float f32x4 __attribute__((ext_vector_type(4)));

static inline size_t alignUp(size_t x) { return (x + 255) & ~size_t(255); }

// fp32 -> bf16 round-to-nearest-even (finite values)
__device__ inline unsigned short f2bf(float f) {
    union { float f; u32 u; } v; v.f = f;
    u32 r = v.u + 0x7fffu + ((v.u >> 16) & 1u);
    return (unsigned short)(r >> 16);
}
__device__ inline float bf_lo(u32 u) { return __uint_as_float(u << 16); }
__device__ inline float bf_hi(u32 u) { return __uint_as_float(u & 0xffff0000u); }

__device__ inline void accum8(float acc[8], uint4 r, float w) {
    acc[0] += w * bf_lo(r.x); acc[1] += w * bf_hi(r.x);
    acc[2] += w * bf_lo(r.y); acc[3] += w * bf_hi(r.y);
    acc[4] += w * bf_lo(r.z); acc[5] += w * bf_hi(r.z);
    acc[6] += w * bf_lo(r.w); acc[7] += w * bf_hi(r.w);
}

// ---------------- prep: W->bf16 transpose (blocks [0,WT_BLOCKS)) + bucket counts ----------------
// Bucket histogram in LDS; flush with consecutive-address (hot-line) atomics only.
// NO per-edge random global atomics anywhere in this pipeline (~64B fabric RMW each).
__global__ __launch_bounds__(256) void prep_kernel(const float* __restrict__ W1,
                                                   const float* __restrict__ W2,
                                                   const float* __restrict__ W3,
                                                   unsigned short* __restrict__ Wt,
                                                   const int* __restrict__ dst,
                                                   u32* __restrict__ bcnt) {
    __shared__ u32 hist[NBUCKET];
    int bid = blockIdx.x;
    if (bid < WT_BLOCKS) {
        int m = bid >> 6;                       // which matrix
        int e = (bid & 63) * 256 + threadIdx.x; // element within 128x128
        int n = e >> 7, k = e & 127;
        const float* W = (m == 0) ? W1 : (m == 1) ? W2 : W3;
        Wt[m * DIM * DIM + n * DIM + k] = f2bf(W[(size_t)k * DIM + n]);
        return;
    }
    int b = bid - WT_BLOCKS;
    for (int k = threadIdx.x; k < NBUCKET; k += 256) hist[k] = 0;
    __syncthreads();
    int e0 = b * P1_CHUNK;
    int e1 = min(e0 + P1_CHUNK, N_EDGES);
    for (int i = e0 + threadIdx.x; i < e1; i += 256)
        atomicAdd(&hist[((u32)dst[i]) >> 8], 1u);
    __syncthreads();
    for (int k = threadIdx.x; k < NBUCKET; k += 256)
        if (hist[k]) atomicAdd(&bcnt[k], hist[k]);
}

// ---------------- bscan: exclusive scan of 196 bucket sizes ----------------
__global__ __launch_bounds__(256) void bscan_kernel(const u32* __restrict__ bcnt,
                                                    u32* __restrict__ bbase,
                                                    u32* __restrict__ bcur) {
    __shared__ u32 wsum[4];
    int tid = threadIdx.x, lane = tid & 63, wv = tid >> 6;
    u32 c = (tid < NBUCKET) ? bcnt[tid] : 0;
    u32 v = c;
#pragma unroll
    for (int off = 1; off < 64; off <<= 1) {
        u32 u = __shfl_up(v, off, 64);
        if (lane >= off) v += u;
    }
    if (lane == 63) wsum[wv] = v;
    __syncthreads();
    u32 wo = 0;
    for (int w = 0; w < wv; w++) wo += wsum[w];
    u32 excl = wo + v - c;
    if (tid < NBUCKET) { bbase[tid] = excl; bcur[tid] = excl; }
}

// ---------------- part: partition edges into bucket-major epart (packed src|dst<<16) ----------
// One reservation atomic per (block,bucket) on hot lines; epart writes are block-private chunks.
__global__ __launch_bounds__(256) void part_kernel(const int* __restrict__ src,
                                                   const int* __restrict__ dst,
                                                   u32* __restrict__ bcur,
                                                   u32* __restrict__ epart) {
    __shared__ u32 ed[P2_CHUNK];
    __shared__ u32 hist[NBUCKET];
    __shared__ u32 cb[NBUCKET];
    __shared__ u32 rk[NBUCKET];
    int tid = threadIdx.x;
    for (int k = tid; k < NBUCKET; k += 256) { hist[k] = 0; rk[k] = 0; }
    __syncthreads();
    int e0 = blockIdx.x * P2_CHUNK;
    int e1 = min(e0 + P2_CHUNK, N_EDGES);
    for (int i = e0 + tid; i < e1; i += 256) {
        u32 s = (u32)src[i], d = (u32)dst[i];
        u32 v = s | (d << 16);
        ed[i - e0] = v;
        atomicAdd(&hist[d >> 8], 1u);
    }
    __syncthreads();
    for (int k = tid; k < NBUCKET; k += 256) {
        u32 c = hist[k];
        cb[k] = c ? atomicAdd(&bcur[k], c) : 0u;
    }
    __syncthreads();
    int n = e1 - e0;
    for (int k = tid; k < n; k += 256) {
        u32 v = ed[k];
        u32 bk = v >> 24;                   // (dst>>8), dst fits 16 bits
        u32 r = atomicAdd(&rk[bk], 1u);     // LDS rank
        epart[cb[bk] + r] = v;
    }
}

// ---------------- K1: MFMA GEMM h(bf16) = x(fp32->bf16) @ Wt^T, + bucket-CSR build ----------
#define LDSTRIDE 40
__global__ __launch_bounds__(256) void gemm_mfma_kernel(const float* __restrict__ x,
                                                        const unsigned short* __restrict__ Wt,
                                                        unsigned short* __restrict__ hb,
                                                        int n_rows,
                                                        const u32* __restrict__ bbase,
                                                        const u32* __restrict__ bcnt,
                                                        const u32* __restrict__ epart,
                                                        int* __restrict__ cnt,
                                                        int* __restrict__ base,
                                                        float* __restrict__ dinv,
                                                        unsigned short* __restrict__ csr16) {
    __shared__ unsigned short As[128 * LDSTRIDE];
    __shared__ unsigned short Bs[128 * LDSTRIDE];
    if (blockIdx.x >= GEMM_BLOCKS) {
        int B = blockIdx.x - GEMM_BLOCKS;   // bucket id
        u32* hcnt = (u32*)&As[0];           // 256 u32
        u32* pref = hcnt + 256;             // 256 u32 (local cursors)
        u32* wsum = pref + 256;             // 4 u32
        int tid = threadIdx.x, lane = tid & 63, wv = tid >> 6;
        int nb0 = B << 8;
        u32 ebeg = bbase[B];
        u32 esz  = bcnt[B];
        hcnt[tid] = 0;
        __syncthreads();
        for (u32 k = tid; k < esz; k += 256)
            atomicAdd(&hcnt[(epart[ebeg + k] >> 16) & 255u], 1u);
        __syncthreads();
        u32 c = hcnt[tid];
        u32 v = c;
#pragma unroll
        for (int off = 1; off < 64; off <<= 1) {
            u32 u = __shfl_up(v, off, 64);
            if (lane >= off) v += u;
        }
        if (lane == 63) wsum[wv] = v;
        __syncthreads();
        u32 wo = 0;
        for (int w = 0; w < wv; w++) wo += wsum[w];
        u32 excl = wo + v - c;              // exclusive prefix within bucket
        int node = nb0 + tid;
        if (node < N_NODES) {
            cnt[node]  = (int)c;
            base[node] = (int)(ebeg + excl);
            dinv[node] = rsqrtf((float)(c + 1));
        }
        pref[tid] = excl;
        __syncthreads();
        for (u32 k = tid; k < esz; k += 256) {
            u32 v2 = epart[ebeg + k];
            u32 dl = (v2 >> 16) & 255u;
            u32 r = atomicAdd(&pref[dl], 1u);   // LDS rank
            csr16[ebeg + r] = (unsigned short)(v2 & 0xffffu);
        }
        return;
    }
    const int tid = threadIdx.x;
    const int wave = tid >> 6;
    const int lane = tid & 63;
    const int quad = lane >> 4;
    const int l16 = lane & 15;
    const int row0 = blockIdx.x * 128;

    f32x4 acc[2][8];
#pragma unroll
    for (int mt = 0; mt < 2; mt++)
#pragma unroll
        for (int nt = 0; nt < 8; nt++) acc[mt][nt] = (f32x4){0.f, 0.f, 0.f, 0.f};

    for (int k0 = 0; k0 < DIM; k0 += 32) {
        // stage A from fp32 input: 4 passes x 32 rows; 8 thr/row, cvt to bf16.
#pragma unroll
        for (int p = 0; p < 4; p++) {
            int r = p * 32 + (tid >> 3);
            int kq = (tid & 7) * 4;
            int gr = row0 + r;
            float4 v = make_float4(0.f, 0.f, 0.f, 0.f);
            if (gr < n_rows) v = *(const float4*)&x[(size_t)gr * DIM + k0 + kq];
            u32 lo = (u32)f2bf(v.x) | ((u32)f2bf(v.y) << 16);
            u32 hi = (u32)f2bf(v.z) | ((u32)f2bf(v.w) << 16);
            *(uint2*)&As[r * LDSTRIDE + kq] = make_uint2(lo, hi);
        }
        // stage B: Bs[n][k] = Wt[n][k0..+31]. 2 passes x 64 rows; 4 thr/row.
#pragma unroll
        for (int p = 0; p < 2; p++) {
            int nn = p * 64 + (tid >> 2);
            int kk = (tid & 3) * 8;
            *(uint4*)&Bs[nn * LDSTRIDE + kk] = *(const uint4*)&Wt[nn * DIM + k0 + kk];
        }
        __syncthreads();
        const int m0 = wave * 32;
        bf16x8 a0 = *(const bf16x8*)&As[(m0 + l16) * LDSTRIDE + quad * 8];
        bf16x8 a1 = *(const bf16x8*)&As[(m0 + 16 + l16) * LDSTRIDE + quad * 8];
#pragma unroll
        for (int nt = 0; nt < 8; nt++) {
            bf16x8 b = *(const bf16x8*)&Bs[(nt * 16 + l16) * LDSTRIDE + quad * 8];
            acc[0][nt] = __builtin_amdgcn_mfma_f32_16x16x32_bf16(a0, b, acc[0][nt], 0, 0, 0);
            acc[1][nt] = __builtin_amdgcn_mfma_f32_16x16x32_bf16(a1, b, acc[1][nt], 0, 0, 0);
        }
        __syncthreads();
    }
    // epilogue: C[row=quad*4+reg][col=lane&15] per 16x16 tile (m89-verified layout)
    const int m0 = wave * 32;
#pragma unroll
    for (int mt = 0; mt < 2; mt++) {
#pragma unroll
        for (int reg = 0; reg < 4; reg++) {
            int gr = row0 + m0 + mt * 16 + quad * 4 + reg;
            if (gr < n_rows) {
#pragma unroll
                for (int nt = 0; nt < 8; nt++)
                    hb[(size_t)gr * DIM + nt * 16 + l16] = f2bf(acc[mt][nt][reg]);
            }
        }
    }
}

// ---------------- K2/K3: fused agg(layer i) + GEMM(layer i+1) ----------------
// Block owns 64 rows. Phase A: stage full W (128x128 bf16) into Bs; each wave
// aggregates its 16 nodes (wave-per-node inner structure identical to agg_kernel),
// applies relu(di*acc + b) and writes the bf16 result row directly into LDS As —
// the inter-layer activation never touches HBM. Phase B (after ONE barrier, only
// needed for Bs — each wave reads only the As rows it wrote): full-K MFMA, no
// further barriers. 782 blocks; LDS 52 KB.
#define FSTRIDE 136   // 272 B rows: 16-B aligned, 2-way bank alias only (free)
__global__ __launch_bounds__(256) void fused_agg_gemm_kernel(
        const uint4* __restrict__ hb_in,
        const unsigned short* __restrict__ Wt,
        const int* __restrict__ cnt,
        const int* __restrict__ basep,
        const unsigned short* __restrict__ csr16,
        const float* __restrict__ dinv,
        const float4* __restrict__ bias4,
        unsigned short* __restrict__ hb_out) {
    __shared__ unsigned short As[64 * FSTRIDE];
    __shared__ unsigned short Bs[128 * FSTRIDE];
    const int tid = threadIdx.x;
    const int wave = tid >> 6;
    const int lane = tid & 63;
    const int g = lane >> 4;
    const int l16 = lane & 15;
    const int row0 = blockIdx.x * 64;

    // stage full Wt into Bs (issued first; latency hides under the agg gathers)
#pragma unroll
    for (int i = 0; i < 8; i++) {
        int idx = i * 256 + tid;
        int n = idx >> 4, k8 = (idx & 15) * 8;
        *(uint4*)&Bs[n * FSTRIDE + k8] = *(const uint4*)&Wt[n * DIM + k8];
    }

    // aggregate 16 nodes per wave -> bf16 rows of As
    for (int t = 0; t < 16; t++) {
        const int lrow = wave * 16 + t;
        const int node = row0 + lrow;
        int deg = 0, start = 0;
        float di = 0.f;
        if (node < N_NODES) { deg = cnt[node]; start = basep[node]; di = dinv[node]; }

        float acc[8];
#pragma unroll
        for (int i = 0; i < 8; i++) acc[i] = 0.f;

        for (int b0 = 0; b0 < deg; b0 += 64) {
            int m = min(64, deg - b0);
            int e = 0; float w = 0.f;
            if (lane < m) {
                e = csr16[start + b0 + lane];
                w = dinv[e];
            }
            int j4 = 0;
            for (; j4 + 16 <= m; j4 += 16) {
                int j0 = j4 + g, j1 = j4 + 4 + g, j2 = j4 + 8 + g, j3 = j4 + 12 + g;
                int s0 = __shfl(e, j0, 64);  float w0 = __shfl(w, j0, 64);
                int s1 = __shfl(e, j1, 64);  float w1 = __shfl(w, j1, 64);
                int s2 = __shfl(e, j2, 64);  float w2 = __shfl(w, j2, 64);
                int s3 = __shfl(e, j3, 64);  float w3 = __shfl(w, j3, 64);
                uint4 r0 = hb_in[(size_t)s0 * 16 + l16];
                uint4 r1 = hb_in[(size_t)s1 * 16 + l16];
                uint4 r2 = hb_in[(size_t)s2 * 16 + l16];
                uint4 r3 = hb_in[(size_t)s3 * 16 + l16];
                accum8(acc, r0, w0);
                accum8(acc, r1, w1);
                accum8(acc, r2, w2);
                accum8(acc, r3, w3);
            }
            for (; j4 + 8 <= m; j4 += 8) {
                int j0 = j4 + g, j1 = j4 + 4 + g;
                int s0 = __shfl(e, j0, 64);  float w0 = __shfl(w, j0, 64);
                int s1 = __shfl(e, j1, 64);  float w1 = __shfl(w, j1, 64);
                uint4 r0 = hb_in[(size_t)s0 * 16 + l16];
                uint4 r1 = hb_in[(size_t)s1 * 16 + l16];
                accum8(acc, r0, w0);
                accum8(acc, r1, w1);
            }
            for (; j4 < m; j4 += 4) {
                int j = j4 + g;
                int jj = (j < m) ? j : 0;
                int s0 = __shfl(e, jj, 64);  float w0 = __shfl(w, jj, 64);
                if (j < m) {
                    uint4 r0 = hb_in[(size_t)s0 * 16 + l16];
                    accum8(acc, r0, w0);
                }
            }
        }
        if (g == 0 && node < N_NODES) {   // self-loop (inner weight = dinv[node])
            uint4 r = hb_in[(size_t)node * 16 + l16];
            accum8(acc, r, di);
        }
#pragma unroll
        for (int i = 0; i < 8; i++) {
            acc[i] += __shfl_xor(acc[i], 16, 64);
            acc[i] += __shfl_xor(acc[i], 32, 64);
        }
        if (g == 0) {
            float4 bv0 = bias4[l16 * 2], bv1 = bias4[l16 * 2 + 1];
            float res[8];
            res[0] = di * acc[0] + bv0.x; res[1] = di * acc[1] + bv0.y;
            res[2] = di * acc[2] + bv0.z; res[3] = di * acc[3] + bv0.w;
            res[4] = di * acc[4] + bv1.x; res[5] = di * acc[5] + bv1.y;
            res[6] = di * acc[6] + bv1.z; res[7] = di * acc[7] + bv1.w;
#pragma unroll
            for (int i = 0; i < 8; i++) res[i] = fmaxf(res[i], 0.f);   // fused layers always relu
            u32 p0 = (u32)f2bf(res[0]) | ((u32)f2bf(res[1]) << 16);
            u32 p1 = (u32)f2bf(res[2]) | ((u32)f2bf(res[3]) << 16);
            u32 p2 = (u32)f2bf(res[4]) | ((u32)f2bf(res[5]) << 16);
            u32 p3 = (u32)f2bf(res[6]) | ((u32)f2bf(res[7]) << 16);
            *(uint4*)&As[lrow * FSTRIDE + l16 * 8] = make_uint4(p0, p1, p2, p3);
        }
    }
    __syncthreads();   // Bs visibility (As rows are wave-local)

    // GEMM: wave owns rows [wave*16, wave*16+16), full K resident, no more barriers
    const int quad = g;
    const int w16 = wave * 16;
    f32x4 gacc[8];
#pragma unroll
    for (int nt = 0; nt < 8; nt++) gacc[nt] = (f32x4){0.f, 0.f, 0.f, 0.f};
#pragma unroll
    for (int ks = 0; ks < 4; ks++) {
        bf16x8 a = *(const bf16x8*)&As[(w16 + l16) * FSTRIDE + ks * 32 + quad * 8];
#pragma unroll
        for (int nt = 0; nt < 8; nt++) {
            bf16x8 b = *(const bf16x8*)&Bs[(nt * 16 + l16) * FSTRIDE + ks * 32 + quad * 8];
            gacc[nt] = __builtin_amdgcn_mfma_f32_16x16x32_bf16(a, b, gacc[nt], 0, 0, 0);
        }
    }
#pragma unroll
    for (int reg = 0; reg < 4; reg++) {
        int gr = row0 + w16 + quad * 4 + reg;
        if (gr < N_NODES) {
#pragma unroll
            for (int nt = 0; nt < 8; nt++)
                hb_out[(size_t)gr * DIM + nt * 16 + l16] = f2bf(gacc[nt][reg]);
        }
    }
}

// ---------------- K4: final aggregation -> fp32 out ----------------
__global__ __launch_bounds__(256) void agg_kernel(const uint4* __restrict__ hb,
                                                  const int* __restrict__ cnt,
                                                  const int* __restrict__ basep,
                                                  const unsigned short* __restrict__ csr16,
                                                  const float* __restrict__ dinv,
                                                  const float4* __restrict__ bias4,
                                                  float* __restrict__ out) {
    const int wave = threadIdx.x >> 6;
    const int lane = threadIdx.x & 63;
    const int node = blockIdx.x * 4 + wave;
    const int g = lane >> 4;
    const int l16 = lane & 15;

    const int deg = cnt[node];
    const float di = dinv[node];
    const int start = basep[node];

    float acc[8];
#pragma unroll
    for (int i = 0; i < 8; i++) acc[i] = 0.f;

    for (int b0 = 0; b0 < deg; b0 += 64) {
        int m = min(64, deg - b0);
        int e = 0; float w = 0.f;
        if (lane < m) {
            e = csr16[start + b0 + lane];
            w = dinv[e];
        }
        int j4 = 0;
        for (; j4 + 16 <= m; j4 += 16) {
            int j0 = j4 + g, j1 = j4 + 4 + g, j2 = j4 + 8 + g, j3 = j4 + 12 + g;
            int s0 = __shfl(e, j0, 64);  float w0 = __shfl(w, j0, 64);
            int s1 = __shfl(e, j1, 64);  float w1 = __shfl(w, j1, 64);
            int s2 = __shfl(e, j2, 64);  float w2 = __shfl(w, j2, 64);
            int s3 = __shfl(e, j3, 64);  float w3 = __shfl(w, j3, 64);
            uint4 r0 = hb[(size_t)s0 * 16 + l16];
            uint4 r1 = hb[(size_t)s1 * 16 + l16];
            uint4 r2 = hb[(size_t)s2 * 16 + l16];
            uint4 r3 = hb[(size_t)s3 * 16 + l16];
            accum8(acc, r0, w0);
            accum8(acc, r1, w1);
            accum8(acc, r2, w2);
            accum8(acc, r3, w3);
        }
        for (; j4 + 8 <= m; j4 += 8) {
            int j0 = j4 + g, j1 = j4 + 4 + g;
            int s0 = __shfl(e, j0, 64);  float w0 = __shfl(w, j0, 64);
            int s1 = __shfl(e, j1, 64);  float w1 = __shfl(w, j1, 64);
            uint4 r0 = hb[(size_t)s0 * 16 + l16];
            uint4 r1 = hb[(size_t)s1 * 16 + l16];
            accum8(acc, r0, w0);
            accum8(acc, r1, w1);
        }
        for (; j4 < m; j4 += 4) {
            int j = j4 + g;
            int jj = (j < m) ? j : 0;
            int s0 = __shfl(e, jj, 64);  float w0 = __shfl(w, jj, 64);
            if (j < m) {
                uint4 r0 = hb[(size_t)s0 * 16 + l16];
                accum8(acc, r0, w0);
            }
        }
    }
    if (g == 0) {   // self-loop
        uint4 r = hb[(size_t)node * 16 + l16];
        accum8(acc, r, di);
    }
#pragma unroll
    for (int i = 0; i < 8; i++) {
        acc[i] += __shfl_xor(acc[i], 16, 64);
        acc[i] += __shfl_xor(acc[i], 32, 64);
    }
    if (g == 0) {
        float4 b0 = bias4[l16 * 2], b1 = bias4[l16 * 2 + 1];
        float4* o = (float4*)(out + (size_t)node * DIM);
        o[l16 * 2]     = make_float4(di * acc[0] + b0.x, di * acc[1] + b0.y,
                                     di * acc[2] + b0.z, di * acc[3] + b0.w);
        o[l16 * 2 + 1] = make_float4(di * acc[4] + b1.x, di * acc[5] + b1.y,
                                     di * acc[6] + b1.z, di * acc[7] + b1.w);
    }
}

// ---------------- launch ----------------

extern "C" void kernel_launch(void* const* d_in, const int* in_sizes, int n_in,
                              void* d_out, int out_size, void* d_ws, size_t ws_size,
                              hipStream_t stream) {
    const float* x  = (const float*)d_in[0];
    const int* ei   = (const int*)d_in[1];
    const float* W1 = (const float*)d_in[2];
    const float* b1 = (const float*)d_in[3];
    const float* W2 = (const float*)d_in[4];
    const float* b2 = (const float*)d_in[5];
    const float* W3 = (const float*)d_in[6];
    const float* b3 = (const float*)d_in[7];
    const int* src = ei;
    const int* dst = ei + N_EDGES;
    float* out = (float*)d_out;

    char* w = (char*)d_ws;
    u32* bcnt  = (u32*)w; w += alignUp((size_t)NBUCKET * 4);
    u32* bbase = (u32*)w; w += alignUp((size_t)NBUCKET * 4);
    u32* bcur  = (u32*)w; w += alignUp((size_t)NBUCKET * 4);
    int* cnt   = (int*)w; w += alignUp((size_t)N_NODES * 4);
    int* base  = (int*)w; w += alignUp((size_t)N_NODES * 4);
    float* dinvb = (float*)w; w += alignUp((size_t)N_NODES * 4);
    u32* epart = (u32*)w; w += alignUp((size_t)N_EDGES * 4);            // bucket-major packed edges
    unsigned short* csr16 = (unsigned short*)w; w += alignUp((size_t)N_EDGES * 2);
    unsigned short* wt = (unsigned short*)w; w += alignUp((size_t)3 * DIM * DIM * 2);
    unsigned short* hbuf  = (unsigned short*)w; w += alignUp((size_t)N_NODES * DIM * 2);
    unsigned short* hbuf2 = (unsigned short*)w; w += alignUp((size_t)N_NODES * DIM * 2);

    hipMemsetAsync(bcnt, 0, (size_t)NBUCKET * 4, stream);

    prep_kernel<<<WT_BLOCKS + P1_BLOCKS, 256, 0, stream>>>(W1, W2, W3, wt, dst, bcnt);
    bscan_kernel<<<1, 256, 0, stream>>>(bcnt, bbase, bcur);
    part_kernel<<<P2_BLOCKS, 256, 0, stream>>>(src, dst, bcur, epart);

    // K1: layer-1 GEMM + bucket-CSR build fused (independent, overlaps MFMA)
    gemm_mfma_kernel<<<GEMM_BLOCKS + NBUCKET, 256, 0, stream>>>(x, wt, hbuf, N_NODES,
                                                                bbase, bcnt, epart,
                                                                cnt, base, dinvb, csr16);
    // K2: agg(layer1)+relu+b1 fused with layer-2 GEMM
    fused_agg_gemm_kernel<<<FUSE_BLOCKS, 256, 0, stream>>>((const uint4*)hbuf, wt + DIM * DIM,
                                                           cnt, base, csr16, dinvb,
                                                           (const float4*)b1, hbuf2);
    // K3: agg(layer2)+relu+b2 fused with layer-3 GEMM (ping-pong back into hbuf)
    fused_agg_gemm_kernel<<<FUSE_BLOCKS, 256, 0, stream>>>((const uint4*)hbuf2, wt + 2 * DIM * DIM,
                                                           cnt, base, csr16, dinvb,
                                                           (const float4*)b2, hbuf);
    // K4: final aggregation -> fp32 out
    agg_kernel<<<N_NODES / 4, 256, 0, stream>>>((const uint4*)hbuf, cnt, base, csr16, dinvb,
                                                (const float4*)b3, out);
}

// Round 6
// 253.936 us; speedup vs baseline: 1.3309x; 1.3309x over previous
//
#include <hip/hip_runtime.h>

#define N_NODES 50000
#define N_EDGES 800000
#define DIM 128
#define WT_BLOCKS 192              // 3 * 128*128 / 256
#define GEMM_BLOCKS ((N_NODES + 63) / 64)   // 782 blocks: ~3/CU, small tail
#define NBUCKET ((N_NODES + 255) / 256)   // 196 buckets of 256 nodes (bucket = dst>>8)
#define P1_BLOCKS 200
#define P1_CHUNK 4000              // P1_BLOCKS * P1_CHUNK == N_EDGES
#define P2_BLOCKS 200
#define P2_CHUNK 4000

typedef unsigned int u32;
typedef short bf16x8 __attribute__((ext_vector_type(8)));
typedef float f32x4 __attribute__((ext_vector_type(4)));

static inline size_t alignUp(size_t x) { return (x + 255) & ~size_t(255); }

// fp32 -> bf16 round-to-nearest-even (finite values)
__device__ inline unsigned short f2bf(float f) {
    union { float f; u32 u; } v; v.f = f;
    u32 r = v.u + 0x7fffu + ((v.u >> 16) & 1u);
    return (unsigned short)(r >> 16);
}
__device__ inline float bf_lo(u32 u) { return __uint_as_float(u << 16); }
__device__ inline float bf_hi(u32 u) { return __uint_as_float(u & 0xffff0000u); }

__device__ inline void accum8(float acc[8], uint4 r, float w) {
    acc[0] += w * bf_lo(r.x); acc[1] += w * bf_hi(r.x);
    acc[2] += w * bf_lo(r.y); acc[3] += w * bf_hi(r.y);
    acc[4] += w * bf_lo(r.z); acc[5] += w * bf_hi(r.z);
    acc[6] += w * bf_lo(r.w); acc[7] += w * bf_hi(r.w);
}

// ---------------- prep: W->bf16 transpose (blocks [0,WT_BLOCKS)) + bucket counts ----------------
// Bucket histogram in LDS; flush with consecutive-address (hot-line) atomics only.
// NO per-edge random global atomics anywhere in this pipeline (~64B fabric RMW each).
__global__ __launch_bounds__(256) void prep_kernel(const float* __restrict__ W1,
                                                   const float* __restrict__ W2,
                                                   const float* __restrict__ W3,
                                                   unsigned short* __restrict__ Wt,
                                                   const int* __restrict__ dst,
                                                   u32* __restrict__ bcnt) {
    __shared__ u32 hist[NBUCKET];
    int bid = blockIdx.x;
    if (bid < WT_BLOCKS) {
        int m = bid >> 6;                       // which matrix
        int e = (bid & 63) * 256 + threadIdx.x; // element within 128x128
        int n = e >> 7, k = e & 127;
        const float* W = (m == 0) ? W1 : (m == 1) ? W2 : W3;
        Wt[m * DIM * DIM + n * DIM + k] = f2bf(W[(size_t)k * DIM + n]);
        return;
    }
    int b = bid - WT_BLOCKS;
    for (int k = threadIdx.x; k < NBUCKET; k += 256) hist[k] = 0;
    __syncthreads();
    int e0 = b * P1_CHUNK;
    int e1 = min(e0 + P1_CHUNK, N_EDGES);
    for (int i = e0 + threadIdx.x; i < e1; i += 256)
        atomicAdd(&hist[((u32)dst[i]) >> 8], 1u);
    __syncthreads();
    for (int k = threadIdx.x; k < NBUCKET; k += 256)
        if (hist[k]) atomicAdd(&bcnt[k], hist[k]);
}

// ---------------- bscan: exclusive scan of 196 bucket sizes ----------------
__global__ __launch_bounds__(256) void bscan_kernel(const u32* __restrict__ bcnt,
                                                    u32* __restrict__ bbase,
                                                    u32* __restrict__ bcur) {
    __shared__ u32 wsum[4];
    int tid = threadIdx.x, lane = tid & 63, wv = tid >> 6;
    u32 c = (tid < NBUCKET) ? bcnt[tid] : 0;
    u32 v = c;
#pragma unroll
    for (int off = 1; off < 64; off <<= 1) {
        u32 u = __shfl_up(v, off, 64);
        if (lane >= off) v += u;
    }
    if (lane == 63) wsum[wv] = v;
    __syncthreads();
    u32 wo = 0;
    for (int w = 0; w < wv; w++) wo += wsum[w];
    u32 excl = wo + v - c;
    if (tid < NBUCKET) { bbase[tid] = excl; bcur[tid] = excl; }
}

// ---------------- part: partition edges into bucket-major epart (packed src|dst<<16) ----------
// One reservation atomic per (block,bucket) on hot lines; epart writes are block-private chunks.
__global__ __launch_bounds__(256) void part_kernel(const int* __restrict__ src,
                                                   const int* __restrict__ dst,
                                                   u32* __restrict__ bcur,
                                                   u32* __restrict__ epart) {
    __shared__ u32 ed[P2_CHUNK];
    __shared__ u32 hist[NBUCKET];
    __shared__ u32 cb[NBUCKET];
    __shared__ u32 rk[NBUCKET];
    int tid = threadIdx.x;
    for (int k = tid; k < NBUCKET; k += 256) { hist[k] = 0; rk[k] = 0; }
    __syncthreads();
    int e0 = blockIdx.x * P2_CHUNK;
    int e1 = min(e0 + P2_CHUNK, N_EDGES);
    for (int i = e0 + tid; i < e1; i += 256) {
        u32 s = (u32)src[i], d = (u32)dst[i];
        u32 v = s | (d << 16);
        ed[i - e0] = v;
        atomicAdd(&hist[d >> 8], 1u);
    }
    __syncthreads();
    for (int k = tid; k < NBUCKET; k += 256) {
        u32 c = hist[k];
        cb[k] = c ? atomicAdd(&bcur[k], c) : 0u;
    }
    __syncthreads();
    int n = e1 - e0;
    for (int k = tid; k < n; k += 256) {
        u32 v = ed[k];
        u32 bk = v >> 24;                   // (dst>>8), dst fits 16 bits
        u32 r = atomicAdd(&rk[bk], 1u);     // LDS rank
        epart[cb[bk] + r] = v;
    }
}

// ---------------- MFMA GEMM: h(bf16) = in @ Wt^T; in = fp32 x (xb==null) or bf16 xb ----------
// 64-row tile x 128 cols, 782 blocks (~3/CU). Block 256 thr = 4 waves; wave owns 16 rows.
// LDS 15.4 KB -> many resident blocks; acc = 32 VGPR/thread.
// Blocks >= GEMM_BLOCKS (layer-1 launch only): bucket-CSR build (see round-2 notes).
#define LDSTRIDE 40
__global__ __launch_bounds__(256) void gemm_mfma_kernel(const float* __restrict__ x,
                                                        const unsigned short* __restrict__ xb,
                                                        const unsigned short* __restrict__ Wt,
                                                        unsigned short* __restrict__ hb,
                                                        int n_rows,
                                                        const u32* __restrict__ bbase,
                                                        const u32* __restrict__ bcnt,
                                                        const u32* __restrict__ epart,
                                                        int* __restrict__ cnt,
                                                        int* __restrict__ base,
                                                        float* __restrict__ dinv,
                                                        unsigned short* __restrict__ csr16) {
    __shared__ unsigned short As[64 * LDSTRIDE];
    __shared__ unsigned short Bs[128 * LDSTRIDE];
    if (blockIdx.x >= GEMM_BLOCKS) {
        int B = blockIdx.x - GEMM_BLOCKS;   // bucket id
        u32* hcnt = (u32*)&As[0];           // 256 u32 (As is 5120 B, enough)
        u32* pref = hcnt + 256;             // 256 u32 (local cursors)
        u32* wsum = pref + 256;             // 4 u32
        int tid = threadIdx.x, lane = tid & 63, wv = tid >> 6;
        int nb0 = B << 8;
        u32 ebeg = bbase[B];
        u32 esz  = bcnt[B];
        hcnt[tid] = 0;
        __syncthreads();
        for (u32 k = tid; k < esz; k += 256)
            atomicAdd(&hcnt[(epart[ebeg + k] >> 16) & 255u], 1u);
        __syncthreads();
        u32 c = hcnt[tid];
        u32 v = c;
#pragma unroll
        for (int off = 1; off < 64; off <<= 1) {
            u32 u = __shfl_up(v, off, 64);
            if (lane >= off) v += u;
        }
        if (lane == 63) wsum[wv] = v;
        __syncthreads();
        u32 wo = 0;
        for (int w = 0; w < wv; w++) wo += wsum[w];
        u32 excl = wo + v - c;              // exclusive prefix within bucket
        int node = nb0 + tid;
        if (node < N_NODES) {
            cnt[node]  = (int)c;
            base[node] = (int)(ebeg + excl);
            dinv[node] = rsqrtf((float)(c + 1));
        }
        pref[tid] = excl;
        __syncthreads();
        for (u32 k = tid; k < esz; k += 256) {
            u32 v2 = epart[ebeg + k];
            u32 dl = (v2 >> 16) & 255u;
            u32 r = atomicAdd(&pref[dl], 1u);   // LDS rank
            csr16[ebeg + r] = (unsigned short)(v2 & 0xffffu);
        }
        return;
    }
    const int tid = threadIdx.x;
    const int wave = tid >> 6;
    const int lane = tid & 63;
    const int quad = lane >> 4;
    const int l16 = lane & 15;
    const int row0 = blockIdx.x * 64;

    f32x4 acc[8];
#pragma unroll
    for (int nt = 0; nt < 8; nt++) acc[nt] = (f32x4){0.f, 0.f, 0.f, 0.f};

    for (int k0 = 0; k0 < DIM; k0 += 32) {
        // stage A: 64 rows x 32 k; 4 thr/row x 8 elements each.
        {
            int r = tid >> 2;
            int kq = (tid & 2) * 8;         // two threads cover k offsets {0,16}... 
            // NOTE: 4 thr/row x 8 els = 32 els; use (tid&3)*8 for offsets {0,8,16,24}
            kq = (tid & 3) * 8;
            int gr = row0 + r;
            if (xb) {
                uint4 v = make_uint4(0u, 0u, 0u, 0u);
                if (gr < n_rows) v = *(const uint4*)&xb[(size_t)gr * DIM + k0 + kq];
                *(uint4*)&As[r * LDSTRIDE + kq] = v;
            } else {
                float4 v0 = make_float4(0.f, 0.f, 0.f, 0.f);
                float4 v1 = make_float4(0.f, 0.f, 0.f, 0.f);
                if (gr < n_rows) {
                    v0 = *(const float4*)&x[(size_t)gr * DIM + k0 + kq];
                    v1 = *(const float4*)&x[(size_t)gr * DIM + k0 + kq + 4];
                }
                u32 p0 = (u32)f2bf(v0.x) | ((u32)f2bf(v0.y) << 16);
                u32 p1 = (u32)f2bf(v0.z) | ((u32)f2bf(v0.w) << 16);
                u32 p2 = (u32)f2bf(v1.x) | ((u32)f2bf(v1.y) << 16);
                u32 p3 = (u32)f2bf(v1.z) | ((u32)f2bf(v1.w) << 16);
                *(uint4*)&As[r * LDSTRIDE + kq] = make_uint4(p0, p1, p2, p3);
            }
        }
        // stage B: Bs[n][k] = Wt[n][k0..+31]. 2 passes x 64 rows; 4 thr/row.
#pragma unroll
        for (int p = 0; p < 2; p++) {
            int nn = p * 64 + (tid >> 2);
            int kk = (tid & 3) * 8;
            *(uint4*)&Bs[nn * LDSTRIDE + kk] = *(const uint4*)&Wt[nn * DIM + k0 + kk];
        }
        __syncthreads();
        const int m0 = wave * 16;
        bf16x8 a = *(const bf16x8*)&As[(m0 + l16) * LDSTRIDE + quad * 8];
#pragma unroll
        for (int nt = 0; nt < 8; nt++) {
            bf16x8 b = *(const bf16x8*)&Bs[(nt * 16 + l16) * LDSTRIDE + quad * 8];
            acc[nt] = __builtin_amdgcn_mfma_f32_16x16x32_bf16(a, b, acc[nt], 0, 0, 0);
        }
        __syncthreads();
    }
    // epilogue: C[row=quad*4+reg][col=lane&15] per 16x16 tile (m89-verified layout)
    const int m0 = wave * 16;
#pragma unroll
    for (int reg = 0; reg < 4; reg++) {
        int gr = row0 + m0 + quad * 4 + reg;
        if (gr < n_rows) {
#pragma unroll
            for (int nt = 0; nt < 8; nt++)
                hb[(size_t)gr * DIM + nt * 16 + l16] = f2bf(acc[nt][reg]);
        }
    }
}

// ---------------- aggregation over bf16 h: one WAVE per node ----------------
// out[i] = dinv[i]*(sum_s dinv[s]*h[s] + dinv[i]*h[i]) + b
// Output: bf16 (outb, layers 1-2 — identical bits to the GEMM's own f2bf of the
// fp32 value, so numerics are unchanged) or fp32 (outf, final layer).
__global__ __launch_bounds__(256) void agg_kernel(const uint4* __restrict__ hb,
                                                  const int* __restrict__ cnt,
                                                  const int* __restrict__ basep,
                                                  const unsigned short* __restrict__ csr16,
                                                  const float* __restrict__ dinv,
                                                  const float4* __restrict__ bias4,
                                                  unsigned short* __restrict__ outb,
                                                  float* __restrict__ outf, int relu) {
    const int wave = threadIdx.x >> 6;
    const int lane = threadIdx.x & 63;
    const int node = blockIdx.x * 4 + wave;
    const int g = lane >> 4;
    const int l16 = lane & 15;

    const int deg = cnt[node];
    const float di = dinv[node];
    const int start = basep[node];

    float acc[8];
#pragma unroll
    for (int i = 0; i < 8; i++) acc[i] = 0.f;

    for (int b0 = 0; b0 < deg; b0 += 64) {
        int m = min(64, deg - b0);
        int e = 0; float w = 0.f;
        if (lane < m) {
            e = csr16[start + b0 + lane];
            w = dinv[e];
        }
        int j4 = 0;
        // 16-edge block: 4 gathers in flight per lane group (MLP for the deg>=16 common case)
        for (; j4 + 16 <= m; j4 += 16) {
            int j0 = j4 + g, j1 = j4 + 4 + g, j2 = j4 + 8 + g, j3 = j4 + 12 + g;
            int s0 = __shfl(e, j0, 64);  float w0 = __shfl(w, j0, 64);
            int s1 = __shfl(e, j1, 64);  float w1 = __shfl(w, j1, 64);
            int s2 = __shfl(e, j2, 64);  float w2 = __shfl(w, j2, 64);
            int s3 = __shfl(e, j3, 64);  float w3 = __shfl(w, j3, 64);
            uint4 r0 = hb[(size_t)s0 * 16 + l16];
            uint4 r1 = hb[(size_t)s1 * 16 + l16];
            uint4 r2 = hb[(size_t)s2 * 16 + l16];
            uint4 r3 = hb[(size_t)s3 * 16 + l16];
            accum8(acc, r0, w0);
            accum8(acc, r1, w1);
            accum8(acc, r2, w2);
            accum8(acc, r3, w3);
        }
        for (; j4 + 8 <= m; j4 += 8) {
            int j0 = j4 + g, j1 = j4 + 4 + g;
            int s0 = __shfl(e, j0, 64);  float w0 = __shfl(w, j0, 64);
            int s1 = __shfl(e, j1, 64);  float w1 = __shfl(w, j1, 64);
            uint4 r0 = hb[(size_t)s0 * 16 + l16];
            uint4 r1 = hb[(size_t)s1 * 16 + l16];
            accum8(acc, r0, w0);
            accum8(acc, r1, w1);
        }
        for (; j4 < m; j4 += 4) {
            int j = j4 + g;
            int jj = (j < m) ? j : 0;
            int s0 = __shfl(e, jj, 64);  float w0 = __shfl(w, jj, 64);
            if (j < m) {
                uint4 r0 = hb[(size_t)s0 * 16 + l16];
                accum8(acc, r0, w0);
            }
        }
    }
    if (g == 0) {   // self-loop (inner weight = dinv[node])
        uint4 r = hb[(size_t)node * 16 + l16];
        accum8(acc, r, di);
    }
#pragma unroll
    for (int i = 0; i < 8; i++) {
        acc[i] += __shfl_xor(acc[i], 16, 64);
        acc[i] += __shfl_xor(acc[i], 32, 64);
    }
    if (g == 0) {
        float4 b0 = bias4[l16 * 2], b1 = bias4[l16 * 2 + 1];
        float res[8];
        res[0] = di * acc[0] + b0.x; res[1] = di * acc[1] + b0.y;
        res[2] = di * acc[2] + b0.z; res[3] = di * acc[3] + b0.w;
        res[4] = di * acc[4] + b1.x; res[5] = di * acc[5] + b1.y;
        res[6] = di * acc[6] + b1.z; res[7] = di * acc[7] + b1.w;
        if (relu) {
#pragma unroll
            for (int i = 0; i < 8; i++) res[i] = fmaxf(res[i], 0.f);
        }
        if (outb) {
            u32 p0 = (u32)f2bf(res[0]) | ((u32)f2bf(res[1]) << 16);
            u32 p1 = (u32)f2bf(res[2]) | ((u32)f2bf(res[3]) << 16);
            u32 p2 = (u32)f2bf(res[4]) | ((u32)f2bf(res[5]) << 16);
            u32 p3 = (u32)f2bf(res[6]) | ((u32)f2bf(res[7]) << 16);
            ((uint4*)outb)[(size_t)node * 16 + l16] = make_uint4(p0, p1, p2, p3);
        } else {
            float4* o = (float4*)(outf + (size_t)node * DIM);
            o[l16 * 2]     = make_float4(res[0], res[1], res[2], res[3]);
            o[l16 * 2 + 1] = make_float4(res[4], res[5], res[6], res[7]);
        }
    }
}

// ---------------- launch ----------------

extern "C" void kernel_launch(void* const* d_in, const int* in_sizes, int n_in,
                              void* d_out, int out_size, void* d_ws, size_t ws_size,
                              hipStream_t stream) {
    const float* x  = (const float*)d_in[0];
    const int* ei   = (const int*)d_in[1];
    const float* W1 = (const float*)d_in[2];
    const float* b1 = (const float*)d_in[3];
    const float* W2 = (const float*)d_in[4];
    const float* b2 = (const float*)d_in[5];
    const float* W3 = (const float*)d_in[6];
    const float* b3 = (const float*)d_in[7];
    const int* src = ei;
    const int* dst = ei + N_EDGES;
    float* out = (float*)d_out;

    char* w = (char*)d_ws;
    u32* bcnt  = (u32*)w; w += alignUp((size_t)NBUCKET * 4);
    u32* bbase = (u32*)w; w += alignUp((size_t)NBUCKET * 4);
    u32* bcur  = (u32*)w; w += alignUp((size_t)NBUCKET * 4);
    int* cnt   = (int*)w; w += alignUp((size_t)N_NODES * 4);
    int* base  = (int*)w; w += alignUp((size_t)N_NODES * 4);
    float* dinvb = (float*)w; w += alignUp((size_t)N_NODES * 4);
    u32* epart = (u32*)w; w += alignUp((size_t)N_EDGES * 4);            // bucket-major packed edges
    unsigned short* csr16 = (unsigned short*)w; w += alignUp((size_t)N_EDGES * 2);
    unsigned short* wt = (unsigned short*)w; w += alignUp((size_t)3 * DIM * DIM * 2);
    unsigned short* hbuf = (unsigned short*)w; w += alignUp((size_t)N_NODES * DIM * 2); // gemm out
    unsigned short* abuf = (unsigned short*)w; w += alignUp((size_t)N_NODES * DIM * 2); // agg out (bf16)

    hipMemsetAsync(bcnt, 0, (size_t)NBUCKET * 4, stream);

    int ablocks = N_NODES / 4;   // one wave per node

    prep_kernel<<<WT_BLOCKS + P1_BLOCKS, 256, 0, stream>>>(W1, W2, W3, wt, dst, bcnt);
    bscan_kernel<<<1, 256, 0, stream>>>(bcnt, bbase, bcur);
    part_kernel<<<P2_BLOCKS, 256, 0, stream>>>(src, dst, bcur, epart);

    // layer 1: bucket-CSR build fused into the GEMM launch (independent, overlaps MFMA)
    gemm_mfma_kernel<<<GEMM_BLOCKS + NBUCKET, 256, 0, stream>>>(x, nullptr, wt, hbuf, N_NODES,
                                                                bbase, bcnt, epart,
                                                                cnt, base, dinvb, csr16);
    agg_kernel<<<ablocks, 256, 0, stream>>>((const uint4*)hbuf, cnt, base, csr16, dinvb,
                                            (const float4*)b1, abuf, nullptr, 1);

    gemm_mfma_kernel<<<GEMM_BLOCKS, 256, 0, stream>>>(nullptr, abuf, wt + DIM * DIM, hbuf,
                                                      N_NODES, nullptr, nullptr, nullptr,
                                                      nullptr, nullptr, nullptr, nullptr);
    agg_kernel<<<ablocks, 256, 0, stream>>>((const uint4*)hbuf, cnt, base, csr16, dinvb,
                                            (const float4*)b2, abuf, nullptr, 1);

    gemm_mfma_kernel<<<GEMM_BLOCKS, 256, 0, stream>>>(nullptr, abuf, wt + 2 * DIM * DIM, hbuf,
                                                      N_NODES, nullptr, nullptr, nullptr,
                                                      nullptr, nullptr, nullptr, nullptr);
    agg_kernel<<<ablocks, 256, 0, stream>>>((const uint4*)hbuf, cnt, base, csr16, dinvb,
                                            (const float4*)b3, nullptr, out, 0);
}

// Round 7
// 251.982 us; speedup vs baseline: 1.3412x; 1.0078x over previous
//
#include <hip/hip_runtime.h>

#define N_NODES 50000
#define N_EDGES 800000
#define DIM 128
#define WT_BLOCKS 192              // 3 * 128*128 / 256
#define GEMM_BLOCKS ((N_NODES + 63) / 64)   // 782 blocks: ~3/CU, small tail
#define NBUCKET ((N_NODES + 255) / 256)   // 196 buckets of 256 nodes (bucket = dst>>8)
#define P1_BLOCKS 200
#define P1_CHUNK 4000              // P1_BLOCKS * P1_CHUNK == N_EDGES
#define P2_BLOCKS 200
#define P2_CHUNK 4000

typedef unsigned int u32;
typedef short bf16x8 __attribute__((ext_vector_type(8)));
typedef float f32x4 __attribute__((ext_vector_type(4)));

static inline size_t alignUp(size_t x) { return (x + 255) & ~size_t(255); }

// fp32 -> bf16 round-to-nearest-even (finite values)
__device__ inline unsigned short f2bf(float f) {
    union { float f; u32 u; } v; v.f = f;
    u32 r = v.u + 0x7fffu + ((v.u >> 16) & 1u);
    return (unsigned short)(r >> 16);
}
__device__ inline float bf_lo(u32 u) { return __uint_as_float(u << 16); }
__device__ inline float bf_hi(u32 u) { return __uint_as_float(u & 0xffff0000u); }

__device__ inline void accum8(float acc[8], uint4 r, float w) {
    acc[0] += w * bf_lo(r.x); acc[1] += w * bf_hi(r.x);
    acc[2] += w * bf_lo(r.y); acc[3] += w * bf_hi(r.y);
    acc[4] += w * bf_lo(r.z); acc[5] += w * bf_hi(r.z);
    acc[6] += w * bf_lo(r.w); acc[7] += w * bf_hi(r.w);
}
__device__ inline void add8(float acc[8], uint4 r) {
    acc[0] += bf_lo(r.x); acc[1] += bf_hi(r.x);
    acc[2] += bf_lo(r.y); acc[3] += bf_hi(r.y);
    acc[4] += bf_lo(r.z); acc[5] += bf_hi(r.z);
    acc[6] += bf_lo(r.w); acc[7] += bf_hi(r.w);
}

// ---------------- prep: W->bf16 transpose (blocks [0,WT_BLOCKS)) + bucket counts ----------------
// Bucket histogram in LDS; flush with consecutive-address (hot-line) atomics only.
// NO per-edge random global atomics anywhere in this pipeline (~64B fabric RMW each).
__global__ __launch_bounds__(256) void prep_kernel(const float* __restrict__ W1,
                                                   const float* __restrict__ W2,
                                                   const float* __restrict__ W3,
                                                   unsigned short* __restrict__ Wt,
                                                   const int* __restrict__ dst,
                                                   u32* __restrict__ bcnt) {
    __shared__ u32 hist[NBUCKET];
    int bid = blockIdx.x;
    if (bid < WT_BLOCKS) {
        int m = bid >> 6;                       // which matrix
        int e = (bid & 63) * 256 + threadIdx.x; // element within 128x128
        int n = e >> 7, k = e & 127;
        const float* W = (m == 0) ? W1 : (m == 1) ? W2 : W3;
        Wt[m * DIM * DIM + n * DIM + k] = f2bf(W[(size_t)k * DIM + n]);
        return;
    }
    int b = bid - WT_BLOCKS;
    for (int k = threadIdx.x; k < NBUCKET; k += 256) hist[k] = 0;
    __syncthreads();
    int e0 = b * P1_CHUNK;
    int e1 = min(e0 + P1_CHUNK, N_EDGES);
    for (int i = e0 + threadIdx.x; i < e1; i += 256)
        atomicAdd(&hist[((u32)dst[i]) >> 8], 1u);
    __syncthreads();
    for (int k = threadIdx.x; k < NBUCKET; k += 256)
        if (hist[k]) atomicAdd(&bcnt[k], hist[k]);
}

// ---------------- bscan: exclusive scan of 196 bucket sizes ----------------
__global__ __launch_bounds__(256) void bscan_kernel(const u32* __restrict__ bcnt,
                                                    u32* __restrict__ bbase,
                                                    u32* __restrict__ bcur) {
    __shared__ u32 wsum[4];
    int tid = threadIdx.x, lane = tid & 63, wv = tid >> 6;
    u32 c = (tid < NBUCKET) ? bcnt[tid] : 0;
    u32 v = c;
#pragma unroll
    for (int off = 1; off < 64; off <<= 1) {
        u32 u = __shfl_up(v, off, 64);
        if (lane >= off) v += u;
    }
    if (lane == 63) wsum[wv] = v;
    __syncthreads();
    u32 wo = 0;
    for (int w = 0; w < wv; w++) wo += wsum[w];
    u32 excl = wo + v - c;
    if (tid < NBUCKET) { bbase[tid] = excl; bcur[tid] = excl; }
}

// ---------------- part: partition edges into bucket-major epart (packed src|dst<<16) ----------
// One reservation atomic per (block,bucket) on hot lines; epart writes are block-private chunks.
__global__ __launch_bounds__(256) void part_kernel(const int* __restrict__ src,
                                                   const int* __restrict__ dst,
                                                   u32* __restrict__ bcur,
                                                   u32* __restrict__ epart) {
    __shared__ u32 ed[P2_CHUNK];
    __shared__ u32 hist[NBUCKET];
    __shared__ u32 cb[NBUCKET];
    __shared__ u32 rk[NBUCKET];
    int tid = threadIdx.x;
    for (int k = tid; k < NBUCKET; k += 256) { hist[k] = 0; rk[k] = 0; }
    __syncthreads();
    int e0 = blockIdx.x * P2_CHUNK;
    int e1 = min(e0 + P2_CHUNK, N_EDGES);
    for (int i = e0 + tid; i < e1; i += 256) {
        u32 s = (u32)src[i], d = (u32)dst[i];
        u32 v = s | (d << 16);
        ed[i - e0] = v;
        atomicAdd(&hist[d >> 8], 1u);
    }
    __syncthreads();
    for (int k = tid; k < NBUCKET; k += 256) {
        u32 c = hist[k];
        cb[k] = c ? atomicAdd(&bcur[k], c) : 0u;
    }
    __syncthreads();
    int n = e1 - e0;
    for (int k = tid; k < n; k += 256) {
        u32 v = ed[k];
        u32 bk = v >> 24;                   // (dst>>8), dst fits 16 bits
        u32 r = atomicAdd(&rk[bk], 1u);     // LDS rank
        epart[cb[bk] + r] = v;
    }
}

// ---------------- MFMA GEMM: h(bf16) = in @ Wt^T; in = fp32 x (xb==null) or bf16 xb ----------
// 64-row tile x 128 cols, 782 blocks (~3/CU). Block 256 thr = 4 waves; wave owns 16 rows.
// LDS 15.4 KB -> many resident blocks; acc = 32 VGPR/thread.
// Blocks >= GEMM_BLOCKS (layer-1 launch only): bucket-CSR build (see round-2 notes).
#define LDSTRIDE 40
__global__ __launch_bounds__(256) void gemm_mfma_kernel(const float* __restrict__ x,
                                                        const unsigned short* __restrict__ xb,
                                                        const unsigned short* __restrict__ Wt,
                                                        unsigned short* __restrict__ hb,
                                                        int n_rows,
                                                        const u32* __restrict__ bbase,
                                                        const u32* __restrict__ bcnt,
                                                        const u32* __restrict__ epart,
                                                        int* __restrict__ cnt,
                                                        int* __restrict__ base,
                                                        float* __restrict__ dinv,
                                                        unsigned short* __restrict__ csr16) {
    __shared__ unsigned short As[64 * LDSTRIDE];
    __shared__ unsigned short Bs[128 * LDSTRIDE];
    if (blockIdx.x >= GEMM_BLOCKS) {
        int B = blockIdx.x - GEMM_BLOCKS;   // bucket id
        u32* hcnt = (u32*)&As[0];           // 256 u32 (As is 5120 B, enough)
        u32* pref = hcnt + 256;             // 256 u32 (local cursors)
        u32* wsum = pref + 256;             // 4 u32
        int tid = threadIdx.x, lane = tid & 63, wv = tid >> 6;
        int nb0 = B << 8;
        u32 ebeg = bbase[B];
        u32 esz  = bcnt[B];
        hcnt[tid] = 0;
        __syncthreads();
        for (u32 k = tid; k < esz; k += 256)
            atomicAdd(&hcnt[(epart[ebeg + k] >> 16) & 255u], 1u);
        __syncthreads();
        u32 c = hcnt[tid];
        u32 v = c;
#pragma unroll
        for (int off = 1; off < 64; off <<= 1) {
            u32 u = __shfl_up(v, off, 64);
            if (lane >= off) v += u;
        }
        if (lane == 63) wsum[wv] = v;
        __syncthreads();
        u32 wo = 0;
        for (int w = 0; w < wv; w++) wo += wsum[w];
        u32 excl = wo + v - c;              // exclusive prefix within bucket
        int node = nb0 + tid;
        if (node < N_NODES) {
            cnt[node]  = (int)c;
            base[node] = (int)(ebeg + excl);
            dinv[node] = rsqrtf((float)(c + 1));
        }
        pref[tid] = excl;
        __syncthreads();
        for (u32 k = tid; k < esz; k += 256) {
            u32 v2 = epart[ebeg + k];
            u32 dl = (v2 >> 16) & 255u;
            u32 r = atomicAdd(&pref[dl], 1u);   // LDS rank
            csr16[ebeg + r] = (unsigned short)(v2 & 0xffffu);
        }
        return;
    }
    const int tid = threadIdx.x;
    const int wave = tid >> 6;
    const int lane = tid & 63;
    const int quad = lane >> 4;
    const int l16 = lane & 15;
    const int row0 = blockIdx.x * 64;

    f32x4 acc[8];
#pragma unroll
    for (int nt = 0; nt < 8; nt++) acc[nt] = (f32x4){0.f, 0.f, 0.f, 0.f};

    for (int k0 = 0; k0 < DIM; k0 += 32) {
        // stage A: 64 rows x 32 k; 4 thr/row x 8 elements each.
        {
            int r = tid >> 2;
            int kq = (tid & 3) * 8;
            int gr = row0 + r;
            if (xb) {
                uint4 v = make_uint4(0u, 0u, 0u, 0u);
                if (gr < n_rows) v = *(const uint4*)&xb[(size_t)gr * DIM + k0 + kq];
                *(uint4*)&As[r * LDSTRIDE + kq] = v;
            } else {
                float4 v0 = make_float4(0.f, 0.f, 0.f, 0.f);
                float4 v1 = make_float4(0.f, 0.f, 0.f, 0.f);
                if (gr < n_rows) {
                    v0 = *(const float4*)&x[(size_t)gr * DIM + k0 + kq];
                    v1 = *(const float4*)&x[(size_t)gr * DIM + k0 + kq + 4];
                }
                u32 p0 = (u32)f2bf(v0.x) | ((u32)f2bf(v0.y) << 16);
                u32 p1 = (u32)f2bf(v0.z) | ((u32)f2bf(v0.w) << 16);
                u32 p2 = (u32)f2bf(v1.x) | ((u32)f2bf(v1.y) << 16);
                u32 p3 = (u32)f2bf(v1.z) | ((u32)f2bf(v1.w) << 16);
                *(uint4*)&As[r * LDSTRIDE + kq] = make_uint4(p0, p1, p2, p3);
            }
        }
        // stage B: Bs[n][k] = Wt[n][k0..+31]. 2 passes x 64 rows; 4 thr/row.
#pragma unroll
        for (int p = 0; p < 2; p++) {
            int nn = p * 64 + (tid >> 2);
            int kk = (tid & 3) * 8;
            *(uint4*)&Bs[nn * LDSTRIDE + kk] = *(const uint4*)&Wt[nn * DIM + k0 + kk];
        }
        __syncthreads();
        const int m0 = wave * 16;
        bf16x8 a = *(const bf16x8*)&As[(m0 + l16) * LDSTRIDE + quad * 8];
#pragma unroll
        for (int nt = 0; nt < 8; nt++) {
            bf16x8 b = *(const bf16x8*)&Bs[(nt * 16 + l16) * LDSTRIDE + quad * 8];
            acc[nt] = __builtin_amdgcn_mfma_f32_16x16x32_bf16(a, b, acc[nt], 0, 0, 0);
        }
        __syncthreads();
    }
    // epilogue: C[row=quad*4+reg][col=lane&15] per 16x16 tile (m89-verified layout)
    const int m0 = wave * 16;
#pragma unroll
    for (int reg = 0; reg < 4; reg++) {
        int gr = row0 + m0 + quad * 4 + reg;
        if (gr < n_rows) {
#pragma unroll
            for (int nt = 0; nt < 8; nt++)
                hb[(size_t)gr * DIM + nt * 16 + l16] = f2bf(acc[nt][reg]);
        }
    }
}

// ---------------- aggregation over bf16 h: one WAVE per node ----------------
// WIN=1 (weighted input, layer 1): rows are h[s]; per-edge weight dinv[s].
//   out_node = di*(sum_s dinv[s]*h[s] + di*h[node]) + b
// WIN=0 (prescaled input, layers 2-3): rows are already dinv[s]*h[s]
//   (prescale propagates through the GEMM since dinv is a row scalar:
//    (dinv*act)@W = dinv*(act@W)).  Self term is exactly +row[node] (weight 1).
//   -> no per-edge dinv gather, half the shuffles, adds instead of fmas.
// Output: outb (bf16, prescaled by dinv[node], relu) or outf (fp32 + bias, final).
template <int WIN>
__global__ __launch_bounds__(256) void agg_kernel(const uint4* __restrict__ hb,
                                                  const int* __restrict__ cnt,
                                                  const int* __restrict__ basep,
                                                  const unsigned short* __restrict__ csr16,
                                                  const float* __restrict__ dinv,
                                                  const float4* __restrict__ bias4,
                                                  unsigned short* __restrict__ outb,
                                                  float* __restrict__ outf, int relu) {
    const int wave = threadIdx.x >> 6;
    const int lane = threadIdx.x & 63;
    const int node = blockIdx.x * 4 + wave;
    const int g = lane >> 4;
    const int l16 = lane & 15;

    const int deg = cnt[node];
    const float di = dinv[node];
    const int start = basep[node];

    float acc[8];
#pragma unroll
    for (int i = 0; i < 8; i++) acc[i] = 0.f;

    for (int b0 = 0; b0 < deg; b0 += 64) {
        int m = min(64, deg - b0);
        int e = 0; float w = 0.f;
        if (lane < m) {
            e = csr16[start + b0 + lane];
            if (WIN) w = dinv[e];
        }
        int j4 = 0;
        // 16-edge block: 4 gathers in flight per lane group (MLP for deg>=16 common case)
        for (; j4 + 16 <= m; j4 += 16) {
            int j0 = j4 + g, j1 = j4 + 4 + g, j2 = j4 + 8 + g, j3 = j4 + 12 + g;
            int s0 = __shfl(e, j0, 64);
            int s1 = __shfl(e, j1, 64);
            int s2 = __shfl(e, j2, 64);
            int s3 = __shfl(e, j3, 64);
            uint4 r0 = hb[(size_t)s0 * 16 + l16];
            uint4 r1 = hb[(size_t)s1 * 16 + l16];
            uint4 r2 = hb[(size_t)s2 * 16 + l16];
            uint4 r3 = hb[(size_t)s3 * 16 + l16];
            if (WIN) {
                float w0 = __shfl(w, j0, 64), w1 = __shfl(w, j1, 64);
                float w2 = __shfl(w, j2, 64), w3 = __shfl(w, j3, 64);
                accum8(acc, r0, w0); accum8(acc, r1, w1);
                accum8(acc, r2, w2); accum8(acc, r3, w3);
            } else {
                add8(acc, r0); add8(acc, r1); add8(acc, r2); add8(acc, r3);
            }
        }
        for (; j4 + 8 <= m; j4 += 8) {
            int j0 = j4 + g, j1 = j4 + 4 + g;
            int s0 = __shfl(e, j0, 64);
            int s1 = __shfl(e, j1, 64);
            uint4 r0 = hb[(size_t)s0 * 16 + l16];
            uint4 r1 = hb[(size_t)s1 * 16 + l16];
            if (WIN) {
                float w0 = __shfl(w, j0, 64), w1 = __shfl(w, j1, 64);
                accum8(acc, r0, w0); accum8(acc, r1, w1);
            } else {
                add8(acc, r0); add8(acc, r1);
            }
        }
        for (; j4 < m; j4 += 4) {
            int j = j4 + g;
            int jj = (j < m) ? j : 0;
            int s0 = __shfl(e, jj, 64);
            if (j < m) {
                uint4 r0 = hb[(size_t)s0 * 16 + l16];
                if (WIN) { float w0 = __shfl(w, jj, 64); accum8(acc, r0, w0); }
                else     { add8(acc, r0); }
            } else if (WIN) {
                (void)__shfl(w, jj, 64);   // keep shuffle wave-uniform
            }
        }
    }
    if (g == 0) {   // self-loop: WIN=1 weight di; WIN=0 row already = di*h[node]
        uint4 r = hb[(size_t)node * 16 + l16];
        if (WIN) accum8(acc, r, di); else add8(acc, r);
    }
#pragma unroll
    for (int i = 0; i < 8; i++) {
        acc[i] += __shfl_xor(acc[i], 16, 64);
        acc[i] += __shfl_xor(acc[i], 32, 64);
    }
    if (g == 0) {
        float4 b0 = bias4[l16 * 2], b1 = bias4[l16 * 2 + 1];
        float res[8];
        res[0] = di * acc[0] + b0.x; res[1] = di * acc[1] + b0.y;
        res[2] = di * acc[2] + b0.z; res[3] = di * acc[3] + b0.w;
        res[4] = di * acc[4] + b1.x; res[5] = di * acc[5] + b1.y;
        res[6] = di * acc[6] + b1.z; res[7] = di * acc[7] + b1.w;
        if (relu) {
#pragma unroll
            for (int i = 0; i < 8; i++) res[i] = fmaxf(res[i], 0.f);
        }
        if (outb) {
            // prescale by dinv[node] for the next layer's unweighted sum
#pragma unroll
            for (int i = 0; i < 8; i++) res[i] *= di;
            u32 p0 = (u32)f2bf(res[0]) | ((u32)f2bf(res[1]) << 16);
            u32 p1 = (u32)f2bf(res[2]) | ((u32)f2bf(res[3]) << 16);
            u32 p2 = (u32)f2bf(res[4]) | ((u32)f2bf(res[5]) << 16);
            u32 p3 = (u32)f2bf(res[6]) | ((u32)f2bf(res[7]) << 16);
            ((uint4*)outb)[(size_t)node * 16 + l16] = make_uint4(p0, p1, p2, p3);
        } else {
            float4* o = (float4*)(outf + (size_t)node * DIM);
            o[l16 * 2]     = make_float4(res[0], res[1], res[2], res[3]);
            o[l16 * 2 + 1] = make_float4(res[4], res[5], res[6], res[7]);
        }
    }
}

// ---------------- launch ----------------

extern "C" void kernel_launch(void* const* d_in, const int* in_sizes, int n_in,
                              void* d_out, int out_size, void* d_ws, size_t ws_size,
                              hipStream_t stream) {
    const float* x  = (const float*)d_in[0];
    const int* ei   = (const int*)d_in[1];
    const float* W1 = (const float*)d_in[2];
    const float* b1 = (const float*)d_in[3];
    const float* W2 = (const float*)d_in[4];
    const float* b2 = (const float*)d_in[5];
    const float* W3 = (const float*)d_in[6];
    const float* b3 = (const float*)d_in[7];
    const int* src = ei;
    const int* dst = ei + N_EDGES;
    float* out = (float*)d_out;

    char* w = (char*)d_ws;
    u32* bcnt  = (u32*)w; w += alignUp((size_t)NBUCKET * 4);
    u32* bbase = (u32*)w; w += alignUp((size_t)NBUCKET * 4);
    u32* bcur  = (u32*)w; w += alignUp((size_t)NBUCKET * 4);
    int* cnt   = (int*)w; w += alignUp((size_t)N_NODES * 4);
    int* base  = (int*)w; w += alignUp((size_t)N_NODES * 4);
    float* dinvb = (float*)w; w += alignUp((size_t)N_NODES * 4);
    u32* epart = (u32*)w; w += alignUp((size_t)N_EDGES * 4);            // bucket-major packed edges
    unsigned short* csr16 = (unsigned short*)w; w += alignUp((size_t)N_EDGES * 2);
    unsigned short* wt = (unsigned short*)w; w += alignUp((size_t)3 * DIM * DIM * 2);
    unsigned short* hbuf = (unsigned short*)w; w += alignUp((size_t)N_NODES * DIM * 2); // gemm out
    unsigned short* abuf = (unsigned short*)w; w += alignUp((size_t)N_NODES * DIM * 2); // agg out (bf16)

    hipMemsetAsync(bcnt, 0, (size_t)NBUCKET * 4, stream);

    int ablocks = N_NODES / 4;   // one wave per node

    prep_kernel<<<WT_BLOCKS + P1_BLOCKS, 256, 0, stream>>>(W1, W2, W3, wt, dst, bcnt);
    bscan_kernel<<<1, 256, 0, stream>>>(bcnt, bbase, bcur);
    part_kernel<<<P2_BLOCKS, 256, 0, stream>>>(src, dst, bcur, epart);

    // layer 1: bucket-CSR build fused into the GEMM launch (independent, overlaps MFMA)
    gemm_mfma_kernel<<<GEMM_BLOCKS + NBUCKET, 256, 0, stream>>>(x, nullptr, wt, hbuf, N_NODES,
                                                                bbase, bcnt, epart,
                                                                cnt, base, dinvb, csr16);
    // agg1: weighted input (hb1 unprescaled), prescaled bf16 output
    agg_kernel<1><<<ablocks, 256, 0, stream>>>((const uint4*)hbuf, cnt, base, csr16, dinvb,
                                               (const float4*)b1, abuf, nullptr, 1);

    gemm_mfma_kernel<<<GEMM_BLOCKS, 256, 0, stream>>>(nullptr, abuf, wt + DIM * DIM, hbuf,
                                                      N_NODES, nullptr, nullptr, nullptr,
                                                      nullptr, nullptr, nullptr, nullptr);
    // agg2: prescaled input -> pure sum; prescaled bf16 output
    agg_kernel<0><<<ablocks, 256, 0, stream>>>((const uint4*)hbuf, cnt, base, csr16, dinvb,
                                               (const float4*)b2, abuf, nullptr, 1);

    gemm_mfma_kernel<<<GEMM_BLOCKS, 256, 0, stream>>>(nullptr, abuf, wt + 2 * DIM * DIM, hbuf,
                                                      N_NODES, nullptr, nullptr, nullptr,
                                                      nullptr, nullptr, nullptr, nullptr);
    // agg3: prescaled input -> pure sum; fp32 output + b3, no relu
    agg_kernel<0><<<ablocks, 256, 0, stream>>>((const uint4*)hbuf, cnt, base, csr16, dinvb,
                                               (const float4*)b3, nullptr, out, 0);
}